// Round 2
// baseline (215.189 us; speedup 1.0000x reference)
//
#include <hip/hip_runtime.h>
#include <math.h>

// GPT attention block: B=8, T=1024, E=768, H=12, D=64. fp32 in/out.
// Round 12: flash attention gets (1) XCD-local block remap — all 8 p-blocks of
// a head share idx&7 so the head's K/V/vt (256KB) stays in one XCD's L2 across
// its ~9.5x reuse; (2) T14 async-STAGE split — next K/V tile is loaded to
// registers at iteration top (latency hidden under compute), ds_written to LDS
// after the post-compute barrier. LDS stays 50KB (3 blocks/CU),
// __launch_bounds__(256,3) guards the occupancy cliff.
// QKV 256x256 8-phase GEMM / proj GEMM / prep unchanged from round 11.

#define B_ 8
#define T_ 1024
#define E_ 768
#define H_ 12
#define D_ 64
#define E3 (3 * E_)

typedef __attribute__((ext_vector_type(8))) short bf16x8;
typedef __attribute__((ext_vector_type(4))) float f32x4;

#define SCALE 0.18033688f // 0.125 * log2(e)

__device__ __forceinline__ unsigned short f2bf(float f) {
    unsigned int u = __builtin_bit_cast(unsigned int, f);
    u += 0x7fffu + ((u >> 16) & 1u);   // RNE
    return (unsigned short)(u >> 16);
}

__device__ __forceinline__ void async_copy16(void* lds, const void* g) {
    __builtin_amdgcn_global_load_lds(
        (const __attribute__((address_space(1))) void*)g,
        (__attribute__((address_space(3))) void*)lds, 16, 0, 0);
}

// ---------------- fused prep: x->bf16, w_attn^T, w_proj^T ----------------
#define NCVT 6144                 // (8192*768/4)/256
#define NTA  (72 * 24)            // (E3/32) x (E_/32)
#define NTP  (24 * 24)            // (E_/32) x (E_/32)

__device__ __forceinline__ void transpose_tile(
    const float* __restrict__ W, unsigned short* __restrict__ Wt,
    int K, int N, int gx, int gy, unsigned short (*tile)[33])
{
    const int n0 = gx * 32, k0 = gy * 32;
    const int tx = threadIdx.x & 31, ty = threadIdx.x >> 5;
    #pragma unroll
    for (int i = 0; i < 4; ++i)
        tile[ty + i * 8][tx] = f2bf(W[(size_t)(k0 + ty + i * 8) * N + n0 + tx]);
    __syncthreads();
    #pragma unroll
    for (int i = 0; i < 4; ++i)
        Wt[(size_t)(n0 + ty + i * 8) * K + k0 + tx] = tile[tx][ty + i * 8];
}

__global__ __launch_bounds__(256) void prep_kernel(
    const float* __restrict__ x, unsigned short* __restrict__ x_bf,
    const float* __restrict__ w_attn, unsigned short* __restrict__ wat,
    const float* __restrict__ w_proj, unsigned short* __restrict__ wpt)
{
    __shared__ unsigned short tile[32][33];
    const int bid = blockIdx.x;
    if (bid < NCVT) {
        const int i = bid * 256 + threadIdx.x;
        float4 f = ((const float4*)x)[i];
        ushort4 o;
        o.x = f2bf(f.x); o.y = f2bf(f.y); o.z = f2bf(f.z); o.w = f2bf(f.w);
        ((ushort4*)x_bf)[i] = o;
    } else if (bid < NCVT + NTA) {
        const int t = bid - NCVT;
        transpose_tile(w_attn, wat, E_, E3, t % 72, t / 72, tile);
    } else {
        const int t = bid - NCVT - NTA;
        transpose_tile(w_proj, wpt, E_, E_, t % 24, t / 24, tile);
    }
}

// ---------------- QKV GEMM: 256x256 tile, 8-phase schedule (unchanged) ----------------
__global__ __launch_bounds__(512, 2) void gemm_qkv_256(
    const unsigned short* __restrict__ A,   // [8192,768] bf16
    const unsigned short* __restrict__ Wt,  // [2304,768] bf16
    const float* __restrict__ bias,
    unsigned short* __restrict__ C,         // [8192,2304] bf16 (Q,K regions)
    unsigned short* __restrict__ vt)        // [B*H*64,1024] bf16
{
    constexpr int K = 768;
    constexpr int N = E3;
    constexpr int NI = 6;                   // K / 128 (2 K-tiles per iteration)

    extern __shared__ unsigned short lds[];
    unsigned short* const Ab0 = lds;                // tile buf0: 256x64
    unsigned short* const Ab1 = lds + 16384;        // tile buf1
    unsigned short* const Bb0 = lds + 32768;
    unsigned short* const Bb1 = lds + 49152;

    const int tid  = threadIdx.x;
    const int lane = tid & 63;
    const int w    = tid >> 6;          // 0..7
    const int wm   = w >> 2;            // 0..1
    const int wn   = w & 3;             // 0..3
    const int n16  = lane & 15;
    const int quad = lane >> 4;
    const int l7   = lane & 7;
    const int lrow = lane >> 3;
    const int lcol = (l7 ^ lrow) * 8;   // pre-swizzled source column group

    // XCD-chunked bijective swizzle: 288 blocks = 8 XCDs x 36 contiguous works
    const int lin  = blockIdx.x;
    const int work = (lin & 7) * 36 + (lin >> 3);
    const int by = work / 9, bx = work % 9;
    const int bm = by * 256, bn = bx * 256;

    const unsigned short* Asrc = A  + (size_t)(bm + w * 16 + lrow) * K + lcol;
    const unsigned short* Bsrc = Wt + (size_t)(bn + w * 16 + lrow) * K + lcol;

    auto stgA = [&](unsigned short* buf, int kt, int h) {
        #pragma unroll
        for (int i = 0; i < 2; ++i)
            async_copy16(&buf[h * 8192 + (w * 2 + i) * 512],
                         Asrc + (size_t)(h * 128 + i * 8) * K + kt * 64);
    };
    auto stgB = [&](unsigned short* buf, int kt, int h) {
        #pragma unroll
        for (int i = 0; i < 2; ++i)
            async_copy16(&buf[h * 8192 + (w * 2 + i) * 512],
                         Bsrc + (size_t)(h * 128 + i * 8) * K + kt * 64);
    };

    bf16x8 afr[8], b0f[4], b1f[4];
    f32x4 acc[8][4] = {};

#define LDA(buf, qm) { \
    _Pragma("unroll") \
    for (int ml = 0; ml < 4; ++ml) { \
        const int r = wm * 16 + ((qm) * 4 + ml) * 32 + n16; \
        const unsigned short* rp = (buf) + r * 64; \
        afr[ml * 2 + 0] = *(const bf16x8*)&rp[((0 + quad) ^ l7) * 8]; \
        afr[ml * 2 + 1] = *(const bf16x8*)&rp[((4 + quad) ^ l7) * 8]; \
    } }
#define LDB(bfr, buf, qn) { \
    _Pragma("unroll") \
    for (int nl = 0; nl < 2; ++nl) { \
        const int r = wn * 16 + ((qn) * 2 + nl) * 64 + n16; \
        const unsigned short* rp = (buf) + r * 64; \
        bfr[nl * 2 + 0] = *(const bf16x8*)&rp[((0 + quad) ^ l7) * 8]; \
        bfr[nl * 2 + 1] = *(const bf16x8*)&rp[((4 + quad) ^ l7) * 8]; \
    } }
#define MM(qm, qn, bfr) { \
    _Pragma("unroll") \
    for (int ml = 0; ml < 4; ++ml) \
    _Pragma("unroll") \
    for (int nl = 0; nl < 2; ++nl) \
    _Pragma("unroll") \
    for (int kk = 0; kk < 2; ++kk) \
        acc[(qm) * 4 + ml][(qn) * 2 + nl] = __builtin_amdgcn_mfma_f32_16x16x32_bf16( \
            afr[ml * 2 + kk], bfr[nl * 2 + kk], acc[(qm) * 4 + ml][(qn) * 2 + nl], 0, 0, 0); }

#define BARR  __builtin_amdgcn_s_barrier()
#define LGKM0 asm volatile("s_waitcnt lgkmcnt(0)" ::: "memory")
#define VM6   asm volatile("s_waitcnt vmcnt(6)" ::: "memory")
#define VM0   asm volatile("s_waitcnt vmcnt(0)" ::: "memory")
#define PRI1  __builtin_amdgcn_s_setprio(1)
#define PRI0  __builtin_amdgcn_s_setprio(0)

    stgA(Ab0, 0, 0); stgB(Bb0, 0, 0); stgB(Bb0, 0, 1); stgA(Ab0, 0, 1);
    stgA(Ab1, 1, 0); stgB(Bb1, 1, 0); stgB(Bb1, 1, 1);
    VM6; BARR;

    #pragma unroll 1
    for (int I = 0; I < NI - 1; ++I) {
        const int u = 2 * I;
        // P1  (tile u, quadrant 0,0)
        LDA(Ab0, 0); LDB(b0f, Bb0, 0);
        stgA(Ab1, u + 1, 1);
        BARR; LGKM0; PRI1; MM(0, 0, b0f); PRI0; BARR;
        // P2  (0,1)
        LDB(b1f, Bb0, 1);
        stgA(Ab0, u + 2, 0);
        BARR; LGKM0; PRI1; MM(0, 1, b1f); PRI0; BARR;
        // P3  (1,1)
        LDA(Ab0, 1);
        stgB(Bb0, u + 2, 0);
        BARR; LGKM0; PRI1; MM(1, 1, b1f); PRI0; BARR;
        // P4  (1,0)
        stgB(Bb0, u + 2, 1);
        BARR; LGKM0; PRI1; MM(1, 0, b0f); PRI0; VM6; BARR;
        // P5  (tile u+1, quadrant 0,0)
        LDA(Ab1, 0); LDB(b0f, Bb1, 0);
        stgA(Ab0, u + 2, 1);
        BARR; LGKM0; PRI1; MM(0, 0, b0f); PRI0; BARR;
        // P6  (0,1)
        LDB(b1f, Bb1, 1);
        stgA(Ab1, u + 3, 0);
        BARR; LGKM0; PRI1; MM(0, 1, b1f); PRI0; BARR;
        // P7  (1,1)
        LDA(Ab1, 1);
        stgB(Bb1, u + 3, 0);
        BARR; LGKM0; PRI1; MM(1, 1, b1f); PRI0; BARR;
        // P8  (1,0)
        stgB(Bb1, u + 3, 1);
        BARR; LGKM0; PRI1; MM(1, 0, b0f); PRI0; VM6; BARR;
    }

    // peeled final iteration (tiles 10, 11)
    LDA(Ab0, 0); LDB(b0f, Bb0, 0);
    stgA(Ab1, 11, 1);
    BARR; LGKM0; PRI1; MM(0, 0, b0f); PRI0; BARR;
    LDB(b1f, Bb0, 1);
    BARR; LGKM0; PRI1; MM(0, 1, b1f); PRI0; BARR;
    LDA(Ab0, 1);
    BARR; LGKM0; PRI1; MM(1, 1, b1f); PRI0; BARR;
    BARR; PRI1; MM(1, 0, b0f); PRI0; VM0; BARR;
    LDA(Ab1, 0); LDB(b0f, Bb1, 0);
    BARR; LGKM0; PRI1; MM(0, 0, b0f); PRI0; BARR;
    LDB(b1f, Bb1, 1);
    BARR; LGKM0; PRI1; MM(0, 1, b1f); PRI0; BARR;
    LDA(Ab1, 1);
    BARR; LGKM0; PRI1; MM(1, 1, b1f); PRI0; BARR;
    PRI1; MM(1, 0, b0f); PRI0;

#undef LDA
#undef LDB
#undef MM

    // ---- epilogue ----
    if (bx >= 6) {
        #pragma unroll
        for (int m = 0; m < 8; ++m) {
            const int tt = bm + wm * 16 + m * 32 + quad * 4;
            const size_t bb = (size_t)(tt >> 10) * 768;
            const int tin = tt & 1023;
            #pragma unroll
            for (int n = 0; n < 4; ++n) {
                const int col = bn + wn * 16 + n * 64 + n16;
                const int ch = col - 1536;
                const float bv = bias[col];
                ushort4 o4;
                o4.x = f2bf(acc[m][n][0] + bv);
                o4.y = f2bf(acc[m][n][1] + bv);
                o4.z = f2bf(acc[m][n][2] + bv);
                o4.w = f2bf(acc[m][n][3] + bv);
                *(ushort4*)&vt[(bb + ch) * 1024 + tin] = o4;
            }
        }
    } else {
        const bool scale_q = bx < 3;
        #pragma unroll
        for (int m = 0; m < 8; ++m) {
            #pragma unroll
            for (int r = 0; r < 4; ++r) {
                const size_t rowoff = (size_t)(bm + wm * 16 + m * 32 + quad * 4 + r) * N;
                #pragma unroll
                for (int n = 0; n < 4; ++n) {
                    const int col = bn + wn * 16 + n * 64 + n16;
                    float v = acc[m][n][r] + bias[col];
                    if (scale_q) v *= SCALE;
                    C[rowoff + col] = f2bf(v);
                }
            }
        }
    }
}

// ---------------- bf16 MFMA GEMM (proj only, unchanged) ----------------
template <typename OutT, int MODE, int BM, int BN, int WR, int WC>
__global__ __launch_bounds__(256) void gemm_mfma_kernel(
    const unsigned short* __restrict__ A,   // [M,K] bf16
    const unsigned short* __restrict__ Wt,  // [N,K] bf16
    const float* __restrict__ bias,
    OutT* __restrict__ C,
    unsigned short* __restrict__ vt,        // MODE 1 only
    int M, int N, int K)
{
    constexpr int MT = BM / WR / 16;
    constexpr int NT = BN / WC / 16;
    constexpr int CA = BM / 32;
    constexpr int CB = BN / 32;
    constexpr int QBX = 768 / BN;
    constexpr int VBX = 1536 / BN;

    __shared__ unsigned short Abuf[BM * 64];
    __shared__ unsigned short Bbuf[BN * 64];

    const int tid = threadIdx.x;
    const int lane = tid & 63;
    const int w = tid >> 6;
    const int n16 = lane & 15;
    const int quad = lane >> 4;

    const int nbx = gridDim.x;
    const int lin = blockIdx.y * nbx + blockIdx.x;
    const int band_sz = 8 * nbx;
    const int band = lin / band_sz;
    const int rr = lin % band_sz;
    const int bm = (band * 8 + (rr & 7)) * BM;
    const int bx = rr >> 3;
    const int bn = bx * BN;

    const int wmbase = (w / WC) * (BM / WR);
    const int wnbase = (w % WC) * (BN / WC);

    const int lrow = lane >> 3;
    const int lcol = ((lane & 7) ^ lrow) * 8;

    f32x4 acc[MT][NT] = {};

    for (int k0 = 0; k0 < K; k0 += 64) {
        __syncthreads();
        #pragma unroll
        for (int i = 0; i < CA; ++i) {
            const int c = w * CA + i;
            const int row = c * 8 + lrow;
            async_copy16(&Abuf[c * 512], A + (size_t)(bm + row) * K + k0 + lcol);
        }
        #pragma unroll
        for (int i = 0; i < CB; ++i) {
            const int c = w * CB + i;
            const int row = c * 8 + lrow;
            async_copy16(&Bbuf[c * 512], Wt + (size_t)(bn + row) * K + k0 + lcol);
        }
        __syncthreads();

        #pragma unroll
        for (int kc = 0; kc < 2; ++kc) {
            bf16x8 af[MT], bf[NT];
            #pragma unroll
            for (int mt = 0; mt < MT; ++mt) {
                const int r = wmbase + mt * 16 + n16;
                af[mt] = *(const bf16x8*)&Abuf[r * 64 + ((kc * 4 + quad) ^ (r & 7)) * 8];
            }
            #pragma unroll
            for (int nt = 0; nt < NT; ++nt) {
                const int r = wnbase + nt * 16 + n16;
                bf[nt] = *(const bf16x8*)&Bbuf[r * 64 + ((kc * 4 + quad) ^ (r & 7)) * 8];
            }
            #pragma unroll
            for (int mt = 0; mt < MT; ++mt)
                #pragma unroll
                for (int nt = 0; nt < NT; ++nt)
                    acc[mt][nt] = __builtin_amdgcn_mfma_f32_16x16x32_bf16(
                        af[mt], bf[nt], acc[mt][nt], 0, 0, 0);
        }
    }

    if (MODE == 1 && bx >= VBX) {
        #pragma unroll
        for (int mt = 0; mt < MT; ++mt) {
            const int tt = bm + wmbase + mt * 16 + quad * 4;
            const size_t bb = (size_t)(tt >> 10) * 768;
            const int tin = tt & 1023;
            #pragma unroll
            for (int nt = 0; nt < NT; ++nt) {
                const int col = bn + wnbase + nt * 16 + n16;
                const int ch = col - 1536;
                const float bv = bias[col];
                ushort4 o4;
                o4.x = f2bf(acc[mt][nt][0] + bv);
                o4.y = f2bf(acc[mt][nt][1] + bv);
                o4.z = f2bf(acc[mt][nt][2] + bv);
                o4.w = f2bf(acc[mt][nt][3] + bv);
                *(ushort4*)&vt[(bb + ch) * 1024 + tin] = o4;
            }
        }
        return;
    }

    const bool scale_q = (MODE == 1) && (bx < QBX);
    #pragma unroll
    for (int mt = 0; mt < MT; ++mt) {
        #pragma unroll
        for (int r = 0; r < 4; ++r) {
            const size_t rowoff = (size_t)(bm + wmbase + mt * 16 + quad * 4 + r) * N;
            #pragma unroll
            for (int nt = 0; nt < NT; ++nt) {
                const int col = bn + wnbase + nt * 16 + n16;
                float v = acc[mt][nt][r] + bias[col];
                if (scale_q) v *= SCALE;
                if constexpr (sizeof(OutT) == 2) C[rowoff + col] = (OutT)f2bf(v);
                else                             C[rowoff + col] = (OutT)v;
            }
        }
    }
}

// ---------------- Flash attention v6: XCD-local remap + async-STAGE split ----------------
#define BKEY 128
#define VSTR 136

__global__ __launch_bounds__(256, 3) void flash_attn_kernel(
    const unsigned short* __restrict__ qkv,
    const unsigned short* __restrict__ vt,   // [(b*H+h)*64+d][1024] bf16
    unsigned short* __restrict__ out)
{
    __shared__ __align__(16) unsigned short Ks[BKEY * 64];
    __shared__ __align__(16) unsigned short Vts[64 * BKEY];
    __shared__ __align__(16) unsigned short Ps[4 * 16 * VSTR];

    const int tid = threadIdx.x;
    // XCD-local remap: all 8 p-blocks of a head share idx&7 (same XCD under
    // round-robin dispatch) -> head's K/V/vt (256KB) stays in one XCD's L2.
    // Per XCD: 12 heads x 256KB = 3MB < 4MB L2.
    const int idx = blockIdx.x;
    const int xcd = idx & 7;
    const int j   = idx >> 3;           // 0..95
    const int head = xcd * 12 + (j % 12);
    const int p    = j / 12;            // 0..7
    const int h = head % H_;
    const int b = head / H_;

    const int lane = tid & 63;
    const int w    = tid >> 6;
    const int n16  = lane & 15;
    const int quad = lane >> 4;

    const size_t base = (size_t)b * T_ * E3;
    const unsigned short* qbase = qkv + base + h * D_;          // pre-scaled q
    const unsigned short* kbase = qkv + base + E_ + h * D_;
    const unsigned short* vtb   = vt + (size_t)(b * H_ + h) * 64 * 1024;

    const int lrow = lane >> 3;
    const int lcol = ((lane & 7) ^ lrow) * 8;
    const int vr4 = lane >> 4;
    const int vc  = lane & 15;

    unsigned short* pw = &Ps[w * 16 * VSTR];

    const int qtA = p, qtB = 15 - p;
    const int nIterA = (qtA + 2) >> 1;
    const int nIterB = (qtB + 2) >> 1;
    const int wqA = qtA * 64 + w * 16;
    const int wqB = qtB * 64 + w * 16;

    const unsigned short* qrpA = qbase + (size_t)(wqA + n16) * E3 + quad * 8;
    bf16x8 qfA0 = *(const bf16x8*)qrpA;
    bf16x8 qfA1 = *(const bf16x8*)(qrpA + 32);
    const unsigned short* qrpB = qbase + (size_t)(wqB + n16) * E3 + quad * 8;
    bf16x8 qfB0 = *(const bf16x8*)qrpB;
    bf16x8 qfB1 = *(const bf16x8*)(qrpB + 32);

    f32x4 oA[4] = {}, oB[4] = {};
    float lsA = 0.f, lsB = 0.f;

    // ---- T14 async-STAGE: K/V tile -> regs (issue early), LDS write late ----
    uint4 kreg[4], vreg[4];
    auto load_tile = [&](int k0) {
        #pragma unroll
        for (int i = 0; i < 4; ++i) {
            const int c = w * 4 + i;
            const int row = c * 8 + lrow;
            kreg[i] = *(const uint4*)(kbase + (size_t)(k0 + row) * E3 + lcol);
        }
        #pragma unroll
        for (int i = 0; i < 4; ++i) {
            const int jj = w * 4 + i;
            const int row = 4 * jj + vr4;
            vreg[i] = *(const uint4*)(vtb + (size_t)row * 1024 + k0 +
                                      ((vc ^ (row & 15)) * 8));
        }
    };
    auto write_tile = [&]() {
        #pragma unroll
        for (int i = 0; i < 4; ++i)
            *(uint4*)((char*)Ks + (size_t)(w * 4 + i) * 1024 + lane * 16) = kreg[i];
        #pragma unroll
        for (int i = 0; i < 4; ++i)
            *(uint4*)((char*)Vts + (size_t)(w * 4 + i) * 1024 + lane * 16) = vreg[i];
    };

    load_tile(0);
    write_tile();
    __syncthreads();

    for (int it = 0; it < nIterB; ++it) {
        const int k0 = it * BKEY;
        const bool pre = (it + 1 < nIterB);
        if (pre) load_tile(k0 + BKEY);     // issue next-tile loads before compute

        // phase computes S^T: mfma(A=K, B=Q) -> rows = keys, cols = q.
        auto phase = [&](bf16x8 qf0, bf16x8 qf1, f32x4* o, float& lsum,
                         int wave_q_min) {
            int knt_lim = ((wave_q_min + 15 - k0) >> 4) + 1;
            if (knt_lim > 8) knt_lim = 8;
            const int ks_lim = (knt_lim + 1) >> 1;
            int Ab2 = wave_q_min - k0 - 15;
            int kfull = Ab2 < 0 ? 0 : (Ab2 >> 4) + 1;
            if (kfull > 8) kfull = 8;

            const int qcol = wave_q_min + n16;           // this lane's q row

            f32x4 s[8];
            #pragma unroll
            for (int knt = 0; knt < 8; ++knt) {
                if (knt < knt_lim) {
                    const int r = knt * 16 + n16;
                    bf16x8 kf0 = *(const bf16x8*)&Ks[r * 64 + ((0 + quad) ^ (r & 7)) * 8];
                    bf16x8 kf1 = *(const bf16x8*)&Ks[r * 64 + ((4 + quad) ^ (r & 7)) * 8];
                    f32x4 acc = {0.f, 0.f, 0.f, 0.f};
                    acc = __builtin_amdgcn_mfma_f32_16x16x32_bf16(kf0, qf0, acc, 0, 0, 0);
                    acc = __builtin_amdgcn_mfma_f32_16x16x32_bf16(kf1, qf1, acc, 0, 0, 0);
                    s[knt] = acc;
                }
            }
            // causal mask: key row (k0+knt*16+quad*4+r) > qcol -> -inf
            #pragma unroll
            for (int knt = 0; knt < 8; ++knt) {
                if (knt >= kfull) {
                    const int krow = k0 + knt * 16 + quad * 4;
                    #pragma unroll
                    for (int r = 0; r < 4; ++r) {
                        float v = (knt < knt_lim) ? s[knt][r] : -1e30f;
                        if (krow + r > qcol) v = -1e30f;
                        s[knt][r] = v;
                    }
                }
            }

            // exp2, lsum (per-lane scalar), pack P[q][key]
            #pragma unroll
            for (int knt = 0; knt < 8; ++knt) {
                float pv0 = __builtin_amdgcn_exp2f(s[knt][0]);
                float pv1 = __builtin_amdgcn_exp2f(s[knt][1]);
                float pv2 = __builtin_amdgcn_exp2f(s[knt][2]);
                float pv3 = __builtin_amdgcn_exp2f(s[knt][3]);
                lsum += (pv0 + pv1) + (pv2 + pv3);
                unsigned int u0 = __builtin_bit_cast(unsigned int, pv0);
                unsigned int u1 = __builtin_bit_cast(unsigned int, pv1);
                unsigned int u2 = __builtin_bit_cast(unsigned int, pv2);
                unsigned int u3 = __builtin_bit_cast(unsigned int, pv3);
                uint2 pk;
                pk.x = ((u0 + 0x8000u) >> 16) | ((u1 + 0x8000u) & 0xffff0000u);
                pk.y = ((u2 + 0x8000u) >> 16) | ((u3 + 0x8000u) & 0xffff0000u);
                *(uint2*)&pw[n16 * VSTR + knt * 16 + quad * 4] = pk;
            }

            // ---- O += P V ----
            #pragma unroll
            for (int ks = 0; ks < 4; ++ks) {
                if (ks < ks_lim) {
                    bf16x8 pf = *(const bf16x8*)&pw[n16 * VSTR + ks * 32 + quad * 8];
                    #pragma unroll
                    for (int dt = 0; dt < 4; ++dt) {
                        const int row = dt * 16 + n16;
                        bf16x8 vf = *(const bf16x8*)&Vts[row * BKEY +
                                        (((ks * 4 + quad) ^ n16) * 8)];
                        o[dt] = __builtin_amdgcn_mfma_f32_16x16x32_bf16(pf, vf, o[dt], 0, 0, 0);
                    }
                }
            }
        };

        phase(qfB0, qfB1, oB, lsB, wqB);
        if (it < nIterA) phase(qfA0, qfA1, oA, lsA, wqA);

        __syncthreads();                   // compute done; prefetch loads landed
        if (pre) {
            write_tile();                  // regs -> LDS for tile it+1
        }
        __syncthreads();
    }

    // ---- final l reduction ----
    lsA += __shfl_xor(lsA, 16); lsA += __shfl_xor(lsA, 32);
    lsB += __shfl_xor(lsB, 16); lsB += __shfl_xor(lsB, 32);

    #pragma unroll
    for (int r = 0; r < 4; ++r) {
        const float invA = 1.f / __shfl(lsA, quad * 4 + r);
        unsigned short* orowA = out + ((size_t)b * T_ + wqA + quad * 4 + r) * E_ + h * D_;
        #pragma unroll
        for (int dt = 0; dt < 4; ++dt)
            orowA[dt * 16 + n16] = f2bf(oA[dt][r] * invA);
        const float invB = 1.f / __shfl(lsB, quad * 4 + r);
        unsigned short* orowB = out + ((size_t)b * T_ + wqB + quad * 4 + r) * E_ + h * D_;
        #pragma unroll
        for (int dt = 0; dt < 4; ++dt)
            orowB[dt * 16 + n16] = f2bf(oB[dt][r] * invB);
    }
}

extern "C" void kernel_launch(void* const* d_in, const int* in_sizes, int n_in,
                              void* d_out, int out_size, void* d_ws, size_t ws_size,
                              hipStream_t stream)
{
    const float* x      = (const float*)d_in[0];
    const float* w_attn = (const float*)d_in[1];
    const float* b_attn = (const float*)d_in[2];
    const float* w_proj = (const float*)d_in[3];
    const float* b_proj = (const float*)d_in[4];
    float* out = (float*)d_out;

    const int M = B_ * T_;  // 8192

    unsigned short* x_bf   = (unsigned short*)d_ws;           // [M,E]
    unsigned short* wat    = x_bf + (size_t)M * E_;           // [3E,E]
    unsigned short* wpt    = wat + (size_t)E3 * E_;           // [E,E]
    unsigned short* qkv_bf = wpt + (size_t)E_ * E_;           // [M,3E] (V region unused)
    unsigned short* att_bf = qkv_bf + (size_t)M * E3;         // [M,E]
    unsigned short* vt_bf  = att_bf + (size_t)M * E_;         // [B*H*64,1024]

    static bool qkv_attr_set = false;
    if (!qkv_attr_set) {
        hipFuncSetAttribute((const void*)gemm_qkv_256,
                            hipFuncAttributeMaxDynamicSharedMemorySize, 131072);
        qkv_attr_set = true;
    }

    prep_kernel<<<NCVT + NTA + NTP, 256, 0, stream>>>(x, x_bf, w_attn, wat, w_proj, wpt);

    gemm_qkv_256<<<dim3(288), dim3(512), 131072, stream>>>(
        x_bf, wat, b_attn, qkv_bf, vt_bf);

    flash_attn_kernel<<<B_ * H_ * 8, 256, 0, stream>>>(qkv_bf, vt_bf, att_bf);

    gemm_mfma_kernel<float, 0, 64, 128, 2, 2>
        <<<dim3(E_ / 128, M / 64), 256, 0, stream>>>(
        att_bf, wpt, b_proj, out, nullptr, M, E_, E_);
}

// Round 3
// 186.463 us; speedup vs baseline: 1.1541x; 1.1541x over previous
//
#include <hip/hip_runtime.h>
#include <math.h>

// GPT attention block: B=8, T=1024, E=768, H=12, D=64. fp32 in/out.
// Round 13: flash v7 — pipelined staging with NO register round-trip (R12's
// reg-staging spilled: 210MB scratch traffic). K is LDS-double-buffered via
// global_load_lds (staged at iter top, used next iter); V single-buffered,
// staged at iter top, counted vmcnt(4) + raw s_barrier after QK+softmax.
// Raw barriers only (no __syncthreads vmcnt(0) drain). Ps LDS buffer deleted:
// P is redistributed C-frag -> A-frag via 8 __shfl + 4 selects per 32-key
// block (fixed cross-quad permutation), LDS 48.3KB keeps 3 blocks/CU.
// b-aligned XCD remap kept (QKV puts batch b in XCD b's L2).
// QKV 256x256 8-phase GEMM / proj GEMM / prep unchanged.

#define B_ 8
#define T_ 1024
#define E_ 768
#define H_ 12
#define D_ 64
#define E3 (3 * E_)

typedef __attribute__((ext_vector_type(8))) short bf16x8;
typedef __attribute__((ext_vector_type(4))) float f32x4;

#define SCALE 0.18033688f // 0.125 * log2(e)

__device__ __forceinline__ unsigned short f2bf(float f) {
    unsigned int u = __builtin_bit_cast(unsigned int, f);
    u += 0x7fffu + ((u >> 16) & 1u);   // RNE
    return (unsigned short)(u >> 16);
}

__device__ __forceinline__ void async_copy16(void* lds, const void* g) {
    __builtin_amdgcn_global_load_lds(
        (const __attribute__((address_space(1))) void*)g,
        (__attribute__((address_space(3))) void*)lds, 16, 0, 0);
}

// ---------------- fused prep: x->bf16, w_attn^T, w_proj^T ----------------
#define NCVT 6144                 // (8192*768/4)/256
#define NTA  (72 * 24)            // (E3/32) x (E_/32)
#define NTP  (24 * 24)            // (E_/32) x (E_/32)

__device__ __forceinline__ void transpose_tile(
    const float* __restrict__ W, unsigned short* __restrict__ Wt,
    int K, int N, int gx, int gy, unsigned short (*tile)[33])
{
    const int n0 = gx * 32, k0 = gy * 32;
    const int tx = threadIdx.x & 31, ty = threadIdx.x >> 5;
    #pragma unroll
    for (int i = 0; i < 4; ++i)
        tile[ty + i * 8][tx] = f2bf(W[(size_t)(k0 + ty + i * 8) * N + n0 + tx]);
    __syncthreads();
    #pragma unroll
    for (int i = 0; i < 4; ++i)
        Wt[(size_t)(n0 + ty + i * 8) * K + k0 + tx] = tile[tx][ty + i * 8];
}

__global__ __launch_bounds__(256) void prep_kernel(
    const float* __restrict__ x, unsigned short* __restrict__ x_bf,
    const float* __restrict__ w_attn, unsigned short* __restrict__ wat,
    const float* __restrict__ w_proj, unsigned short* __restrict__ wpt)
{
    __shared__ unsigned short tile[32][33];
    const int bid = blockIdx.x;
    if (bid < NCVT) {
        const int i = bid * 256 + threadIdx.x;
        float4 f = ((const float4*)x)[i];
        ushort4 o;
        o.x = f2bf(f.x); o.y = f2bf(f.y); o.z = f2bf(f.z); o.w = f2bf(f.w);
        ((ushort4*)x_bf)[i] = o;
    } else if (bid < NCVT + NTA) {
        const int t = bid - NCVT;
        transpose_tile(w_attn, wat, E_, E3, t % 72, t / 72, tile);
    } else {
        const int t = bid - NCVT - NTA;
        transpose_tile(w_proj, wpt, E_, E_, t % 24, t / 24, tile);
    }
}

// ---------------- QKV GEMM: 256x256 tile, 8-phase schedule (unchanged) ----------------
__global__ __launch_bounds__(512, 2) void gemm_qkv_256(
    const unsigned short* __restrict__ A,   // [8192,768] bf16
    const unsigned short* __restrict__ Wt,  // [2304,768] bf16
    const float* __restrict__ bias,
    unsigned short* __restrict__ C,         // [8192,2304] bf16 (Q,K regions)
    unsigned short* __restrict__ vt)        // [B*H*64,1024] bf16
{
    constexpr int K = 768;
    constexpr int N = E3;
    constexpr int NI = 6;                   // K / 128 (2 K-tiles per iteration)

    extern __shared__ unsigned short lds[];
    unsigned short* const Ab0 = lds;                // tile buf0: 256x64
    unsigned short* const Ab1 = lds + 16384;        // tile buf1
    unsigned short* const Bb0 = lds + 32768;
    unsigned short* const Bb1 = lds + 49152;

    const int tid  = threadIdx.x;
    const int lane = tid & 63;
    const int w    = tid >> 6;          // 0..7
    const int wm   = w >> 2;            // 0..1
    const int wn   = w & 3;             // 0..3
    const int n16  = lane & 15;
    const int quad = lane >> 4;
    const int l7   = lane & 7;
    const int lrow = lane >> 3;
    const int lcol = (l7 ^ lrow) * 8;   // pre-swizzled source column group

    // XCD-chunked bijective swizzle: 288 blocks = 8 XCDs x 36 contiguous works
    const int lin  = blockIdx.x;
    const int work = (lin & 7) * 36 + (lin >> 3);
    const int by = work / 9, bx = work % 9;
    const int bm = by * 256, bn = bx * 256;

    const unsigned short* Asrc = A  + (size_t)(bm + w * 16 + lrow) * K + lcol;
    const unsigned short* Bsrc = Wt + (size_t)(bn + w * 16 + lrow) * K + lcol;

    auto stgA = [&](unsigned short* buf, int kt, int h) {
        #pragma unroll
        for (int i = 0; i < 2; ++i)
            async_copy16(&buf[h * 8192 + (w * 2 + i) * 512],
                         Asrc + (size_t)(h * 128 + i * 8) * K + kt * 64);
    };
    auto stgB = [&](unsigned short* buf, int kt, int h) {
        #pragma unroll
        for (int i = 0; i < 2; ++i)
            async_copy16(&buf[h * 8192 + (w * 2 + i) * 512],
                         Bsrc + (size_t)(h * 128 + i * 8) * K + kt * 64);
    };

    bf16x8 afr[8], b0f[4], b1f[4];
    f32x4 acc[8][4] = {};

#define LDA(buf, qm) { \
    _Pragma("unroll") \
    for (int ml = 0; ml < 4; ++ml) { \
        const int r = wm * 16 + ((qm) * 4 + ml) * 32 + n16; \
        const unsigned short* rp = (buf) + r * 64; \
        afr[ml * 2 + 0] = *(const bf16x8*)&rp[((0 + quad) ^ l7) * 8]; \
        afr[ml * 2 + 1] = *(const bf16x8*)&rp[((4 + quad) ^ l7) * 8]; \
    } }
#define LDB(bfr, buf, qn) { \
    _Pragma("unroll") \
    for (int nl = 0; nl < 2; ++nl) { \
        const int r = wn * 16 + ((qn) * 2 + nl) * 64 + n16; \
        const unsigned short* rp = (buf) + r * 64; \
        bfr[nl * 2 + 0] = *(const bf16x8*)&rp[((0 + quad) ^ l7) * 8]; \
        bfr[nl * 2 + 1] = *(const bf16x8*)&rp[((4 + quad) ^ l7) * 8]; \
    } }
#define MM(qm, qn, bfr) { \
    _Pragma("unroll") \
    for (int ml = 0; ml < 4; ++ml) \
    _Pragma("unroll") \
    for (int nl = 0; nl < 2; ++nl) \
    _Pragma("unroll") \
    for (int kk = 0; kk < 2; ++kk) \
        acc[(qm) * 4 + ml][(qn) * 2 + nl] = __builtin_amdgcn_mfma_f32_16x16x32_bf16( \
            afr[ml * 2 + kk], bfr[nl * 2 + kk], acc[(qm) * 4 + ml][(qn) * 2 + nl], 0, 0, 0); }

#define BARR  __builtin_amdgcn_s_barrier()
#define LGKM0 asm volatile("s_waitcnt lgkmcnt(0)" ::: "memory")
#define VM6   asm volatile("s_waitcnt vmcnt(6)" ::: "memory")
#define VM0   asm volatile("s_waitcnt vmcnt(0)" ::: "memory")
#define PRI1  __builtin_amdgcn_s_setprio(1)
#define PRI0  __builtin_amdgcn_s_setprio(0)

    stgA(Ab0, 0, 0); stgB(Bb0, 0, 0); stgB(Bb0, 0, 1); stgA(Ab0, 0, 1);
    stgA(Ab1, 1, 0); stgB(Bb1, 1, 0); stgB(Bb1, 1, 1);
    VM6; BARR;

    #pragma unroll 1
    for (int I = 0; I < NI - 1; ++I) {
        const int u = 2 * I;
        // P1  (tile u, quadrant 0,0)
        LDA(Ab0, 0); LDB(b0f, Bb0, 0);
        stgA(Ab1, u + 1, 1);
        BARR; LGKM0; PRI1; MM(0, 0, b0f); PRI0; BARR;
        // P2  (0,1)
        LDB(b1f, Bb0, 1);
        stgA(Ab0, u + 2, 0);
        BARR; LGKM0; PRI1; MM(0, 1, b1f); PRI0; BARR;
        // P3  (1,1)
        LDA(Ab0, 1);
        stgB(Bb0, u + 2, 0);
        BARR; LGKM0; PRI1; MM(1, 1, b1f); PRI0; BARR;
        // P4  (1,0)
        stgB(Bb0, u + 2, 1);
        BARR; LGKM0; PRI1; MM(1, 0, b0f); PRI0; VM6; BARR;
        // P5  (tile u+1, quadrant 0,0)
        LDA(Ab1, 0); LDB(b0f, Bb1, 0);
        stgA(Ab0, u + 2, 1);
        BARR; LGKM0; PRI1; MM(0, 0, b0f); PRI0; BARR;
        // P6  (0,1)
        LDB(b1f, Bb1, 1);
        stgA(Ab1, u + 3, 0);
        BARR; LGKM0; PRI1; MM(0, 1, b1f); PRI0; BARR;
        // P7  (1,1)
        LDA(Ab1, 1);
        stgB(Bb1, u + 3, 0);
        BARR; LGKM0; PRI1; MM(1, 1, b1f); PRI0; BARR;
        // P8  (1,0)
        stgB(Bb1, u + 3, 1);
        BARR; LGKM0; PRI1; MM(1, 0, b0f); PRI0; VM6; BARR;
    }

    // peeled final iteration (tiles 10, 11)
    LDA(Ab0, 0); LDB(b0f, Bb0, 0);
    stgA(Ab1, 11, 1);
    BARR; LGKM0; PRI1; MM(0, 0, b0f); PRI0; BARR;
    LDB(b1f, Bb0, 1);
    BARR; LGKM0; PRI1; MM(0, 1, b1f); PRI0; BARR;
    LDA(Ab0, 1);
    BARR; LGKM0; PRI1; MM(1, 1, b1f); PRI0; BARR;
    BARR; PRI1; MM(1, 0, b0f); PRI0; VM0; BARR;
    LDA(Ab1, 0); LDB(b0f, Bb1, 0);
    BARR; LGKM0; PRI1; MM(0, 0, b0f); PRI0; BARR;
    LDB(b1f, Bb1, 1);
    BARR; LGKM0; PRI1; MM(0, 1, b1f); PRI0; BARR;
    LDA(Ab1, 1);
    BARR; LGKM0; PRI1; MM(1, 1, b1f); PRI0; BARR;
    PRI1; MM(1, 0, b0f); PRI0;

#undef LDA
#undef LDB
#undef MM

    // ---- epilogue ----
    if (bx >= 6) {
        #pragma unroll
        for (int m = 0; m < 8; ++m) {
            const int tt = bm + wm * 16 + m * 32 + quad * 4;
            const size_t bb = (size_t)(tt >> 10) * 768;
            const int tin = tt & 1023;
            #pragma unroll
            for (int n = 0; n < 4; ++n) {
                const int col = bn + wn * 16 + n * 64 + n16;
                const int ch = col - 1536;
                const float bv = bias[col];
                ushort4 o4;
                o4.x = f2bf(acc[m][n][0] + bv);
                o4.y = f2bf(acc[m][n][1] + bv);
                o4.z = f2bf(acc[m][n][2] + bv);
                o4.w = f2bf(acc[m][n][3] + bv);
                *(ushort4*)&vt[(bb + ch) * 1024 + tin] = o4;
            }
        }
    } else {
        const bool scale_q = bx < 3;
        #pragma unroll
        for (int m = 0; m < 8; ++m) {
            #pragma unroll
            for (int r = 0; r < 4; ++r) {
                const size_t rowoff = (size_t)(bm + wm * 16 + m * 32 + quad * 4 + r) * N;
                #pragma unroll
                for (int n = 0; n < 4; ++n) {
                    const int col = bn + wn * 16 + n * 64 + n16;
                    float v = acc[m][n][r] + bias[col];
                    if (scale_q) v *= SCALE;
                    C[rowoff + col] = f2bf(v);
                }
            }
        }
    }
}

// ---------------- bf16 MFMA GEMM (proj only, unchanged) ----------------
template <typename OutT, int MODE, int BM, int BN, int WR, int WC>
__global__ __launch_bounds__(256) void gemm_mfma_kernel(
    const unsigned short* __restrict__ A,   // [M,K] bf16
    const unsigned short* __restrict__ Wt,  // [N,K] bf16
    const float* __restrict__ bias,
    OutT* __restrict__ C,
    unsigned short* __restrict__ vt,        // MODE 1 only
    int M, int N, int K)
{
    constexpr int MT = BM / WR / 16;
    constexpr int NT = BN / WC / 16;
    constexpr int CA = BM / 32;
    constexpr int CB = BN / 32;
    constexpr int QBX = 768 / BN;
    constexpr int VBX = 1536 / BN;

    __shared__ unsigned short Abuf[BM * 64];
    __shared__ unsigned short Bbuf[BN * 64];

    const int tid = threadIdx.x;
    const int lane = tid & 63;
    const int w = tid >> 6;
    const int n16 = lane & 15;
    const int quad = lane >> 4;

    const int nbx = gridDim.x;
    const int lin = blockIdx.y * nbx + blockIdx.x;
    const int band_sz = 8 * nbx;
    const int band = lin / band_sz;
    const int rr = lin % band_sz;
    const int bm = (band * 8 + (rr & 7)) * BM;
    const int bx = rr >> 3;
    const int bn = bx * BN;

    const int wmbase = (w / WC) * (BM / WR);
    const int wnbase = (w % WC) * (BN / WC);

    const int lrow = lane >> 3;
    const int lcol = ((lane & 7) ^ lrow) * 8;

    f32x4 acc[MT][NT] = {};

    for (int k0 = 0; k0 < K; k0 += 64) {
        __syncthreads();
        #pragma unroll
        for (int i = 0; i < CA; ++i) {
            const int c = w * CA + i;
            const int row = c * 8 + lrow;
            async_copy16(&Abuf[c * 512], A + (size_t)(bm + row) * K + k0 + lcol);
        }
        #pragma unroll
        for (int i = 0; i < CB; ++i) {
            const int c = w * CB + i;
            const int row = c * 8 + lrow;
            async_copy16(&Bbuf[c * 512], Wt + (size_t)(bn + row) * K + k0 + lcol);
        }
        __syncthreads();

        #pragma unroll
        for (int kc = 0; kc < 2; ++kc) {
            bf16x8 af[MT], bf[NT];
            #pragma unroll
            for (int mt = 0; mt < MT; ++mt) {
                const int r = wmbase + mt * 16 + n16;
                af[mt] = *(const bf16x8*)&Abuf[r * 64 + ((kc * 4 + quad) ^ (r & 7)) * 8];
            }
            #pragma unroll
            for (int nt = 0; nt < NT; ++nt) {
                const int r = wnbase + nt * 16 + n16;
                bf[nt] = *(const bf16x8*)&Bbuf[r * 64 + ((kc * 4 + quad) ^ (r & 7)) * 8];
            }
            #pragma unroll
            for (int mt = 0; mt < MT; ++mt)
                #pragma unroll
                for (int nt = 0; nt < NT; ++nt)
                    acc[mt][nt] = __builtin_amdgcn_mfma_f32_16x16x32_bf16(
                        af[mt], bf[nt], acc[mt][nt], 0, 0, 0);
        }
    }

    if (MODE == 1 && bx >= VBX) {
        #pragma unroll
        for (int mt = 0; mt < MT; ++mt) {
            const int tt = bm + wmbase + mt * 16 + quad * 4;
            const size_t bb = (size_t)(tt >> 10) * 768;
            const int tin = tt & 1023;
            #pragma unroll
            for (int nt = 0; nt < NT; ++nt) {
                const int col = bn + wnbase + nt * 16 + n16;
                const int ch = col - 1536;
                const float bv = bias[col];
                ushort4 o4;
                o4.x = f2bf(acc[mt][nt][0] + bv);
                o4.y = f2bf(acc[mt][nt][1] + bv);
                o4.z = f2bf(acc[mt][nt][2] + bv);
                o4.w = f2bf(acc[mt][nt][3] + bv);
                *(ushort4*)&vt[(bb + ch) * 1024 + tin] = o4;
            }
        }
        return;
    }

    const bool scale_q = (MODE == 1) && (bx < QBX);
    #pragma unroll
    for (int mt = 0; mt < MT; ++mt) {
        #pragma unroll
        for (int r = 0; r < 4; ++r) {
            const size_t rowoff = (size_t)(bm + wmbase + mt * 16 + quad * 4 + r) * N;
            #pragma unroll
            for (int nt = 0; nt < NT; ++nt) {
                const int col = bn + wnbase + nt * 16 + n16;
                float v = acc[mt][nt][r] + bias[col];
                if (scale_q) v *= SCALE;
                if constexpr (sizeof(OutT) == 2) C[rowoff + col] = (OutT)f2bf(v);
                else                             C[rowoff + col] = (OutT)v;
            }
        }
    }
}

// ---------------- Flash attention v7: pipelined LDS staging, no Ps ----------------
#define BKEY 128

__global__ __launch_bounds__(256, 3) void flash_attn_kernel(
    const unsigned short* __restrict__ qkv,
    const unsigned short* __restrict__ vt,   // [(b*H+h)*64+d][1024] bf16
    unsigned short* __restrict__ out)
{
    __shared__ __align__(16) unsigned short Ks[2][BKEY * 64];   // double-buffered K
    __shared__ __align__(16) unsigned short Vts[64 * BKEY];     // single-buffered V^T

    const int tid = threadIdx.x;
    // b-aligned XCD remap: QKV's XCD-chunked swizzle writes batch b's K/vt rows
    // through XCD b's L2; run batch b's heads on XCD b (= idx&7 under RR dispatch).
    const int idx = blockIdx.x;
    const int xcd = idx & 7;
    const int j   = idx >> 3;           // 0..95
    const int head = xcd * 12 + (j % 12);
    const int p    = j / 12;            // 0..7
    const int h = head % H_;
    const int b = head / H_;

    const int lane = tid & 63;
    const int w    = tid >> 6;
    const int n16  = lane & 15;
    const int quad = lane >> 4;

    const size_t base = (size_t)b * T_ * E3;
    const unsigned short* qbase = qkv + base + h * D_;          // pre-scaled q
    const unsigned short* kbase = qkv + base + E_ + h * D_;
    const unsigned short* vtb   = vt + (size_t)(b * H_ + h) * 64 * 1024;

    const int lrow = lane >> 3;
    const int lcol = ((lane & 7) ^ lrow) * 8;
    const int vr4 = lane >> 4;
    const int vc  = lane & 15;

    const int qtA = p, qtB = 15 - p;
    const int nIterA = (qtA + 2) >> 1;
    const int nIterB = (qtB + 2) >> 1;
    const int wqA = qtA * 64 + w * 16;
    const int wqB = qtB * 64 + w * 16;

    const unsigned short* qrpA = qbase + (size_t)(wqA + n16) * E3 + quad * 8;
    bf16x8 qfA0 = *(const bf16x8*)qrpA;
    bf16x8 qfA1 = *(const bf16x8*)(qrpA + 32);
    const unsigned short* qrpB = qbase + (size_t)(wqB + n16) * E3 + quad * 8;
    bf16x8 qfB0 = *(const bf16x8*)qrpB;
    bf16x8 qfB1 = *(const bf16x8*)(qrpB + 32);

    f32x4 oA[4] = {}, oB[4] = {};
    float lsA = 0.f, lsB = 0.f;

    // P-frag redistribution lanes: target (n16,Q) gathers from lanes
    // n16 + 32*(Q&1) (+16): derived from S^T C-layout -> PV A-layout mapping.
    const int sLo = n16 + 32 * (quad & 1);
    const int sHi = sLo + 16;
    const bool hiSel = quad >= 2;

    auto stageK = [&](int t) {                 // K tile t -> Ks[t&1] (4 loads)
        unsigned short* dst = Ks[t & 1];
        const int k0 = t * BKEY;
        #pragma unroll
        for (int i = 0; i < 4; ++i) {
            const int c = w * 4 + i;
            const int row = c * 8 + lrow;
            async_copy16(&dst[c * 512], kbase + (size_t)(k0 + row) * E3 + lcol);
        }
    };
    auto stageV = [&](int t) {                 // V tile t -> Vts (4 loads)
        const int k0 = t * BKEY;
        #pragma unroll
        for (int i = 0; i < 4; ++i) {
            const int jj = w * 4 + i;
            const int row = 4 * jj + vr4;
            async_copy16(&Vts[4 * jj * BKEY],
                         vtb + (size_t)row * 1024 + k0 + ((vc ^ (row & 15)) * 8));
        }
    };

    // phase: QK^T (S^T), softmax, [mid wait+barrier], PV with shfl-built P frags
    auto phase = [&](bf16x8 qf0, bf16x8 qf1, f32x4* o, float& lsum,
                     int wave_q_min, int k0, const unsigned short* Kb,
                     bool doMid, bool notLast) {
        int knt_lim = ((wave_q_min + 15 - k0) >> 4) + 1;
        if (knt_lim > 8) knt_lim = 8;
        const int ks_lim = (knt_lim + 1) >> 1;
        const int nkp = ks_lim * 2;
        int Ab2 = wave_q_min - k0 - 15;
        int kfull = Ab2 < 0 ? 0 : (Ab2 >> 4) + 1;
        if (kfull > 8) kfull = 8;

        const int qcol = wave_q_min + n16;           // this lane's q row

        f32x4 s[8];
        #pragma unroll
        for (int knt = 0; knt < 8; ++knt) {
            if (knt < knt_lim) {
                const int r = knt * 16 + n16;
                bf16x8 kf0 = *(const bf16x8*)&Kb[r * 64 + ((0 + quad) ^ (r & 7)) * 8];
                bf16x8 kf1 = *(const bf16x8*)&Kb[r * 64 + ((4 + quad) ^ (r & 7)) * 8];
                f32x4 acc = {0.f, 0.f, 0.f, 0.f};
                acc = __builtin_amdgcn_mfma_f32_16x16x32_bf16(kf0, qf0, acc, 0, 0, 0);
                acc = __builtin_amdgcn_mfma_f32_16x16x32_bf16(kf1, qf1, acc, 0, 0, 0);
                s[knt] = acc;
            }
        }
        // causal mask: key row (k0+knt*16+quad*4+r) > qcol -> -inf
        #pragma unroll
        for (int knt = 0; knt < 8; ++knt) {
            if (knt >= kfull && knt < nkp) {
                const int krow = k0 + knt * 16 + quad * 4;
                #pragma unroll
                for (int r = 0; r < 4; ++r) {
                    float v = (knt < knt_lim) ? s[knt][r] : -1e30f;
                    if (krow + r > qcol) v = -1e30f;
                    s[knt][r] = v;
                }
            }
        }

        // exp2, lsum, pack P -> per-lane bf16 pairs (only knt < nkp is consumed)
        unsigned int e0[8], e1[8];
        #pragma unroll
        for (int knt = 0; knt < 8; ++knt) {
            if (knt < nkp) {
                float pv0 = __builtin_amdgcn_exp2f(s[knt][0]);
                float pv1 = __builtin_amdgcn_exp2f(s[knt][1]);
                float pv2 = __builtin_amdgcn_exp2f(s[knt][2]);
                float pv3 = __builtin_amdgcn_exp2f(s[knt][3]);
                lsum += (pv0 + pv1) + (pv2 + pv3);
                unsigned int u0 = __builtin_bit_cast(unsigned int, pv0);
                unsigned int u1 = __builtin_bit_cast(unsigned int, pv1);
                unsigned int u2 = __builtin_bit_cast(unsigned int, pv2);
                unsigned int u3 = __builtin_bit_cast(unsigned int, pv3);
                e0[knt] = ((u0 + 0x8000u) >> 16) | ((u1 + 0x8000u) & 0xffff0000u);
                e1[knt] = ((u2 + 0x8000u) >> 16) | ((u3 + 0x8000u) & 0xffff0000u);
            }
        }

        if (doMid) {
            // own V[t] (and older) landed; K[t+1] may stay in flight
            if (notLast) asm volatile("s_waitcnt vmcnt(4)" ::: "memory");
            else         asm volatile("s_waitcnt vmcnt(0)" ::: "memory");
            __builtin_amdgcn_s_barrier();
        }

        // ---- O += P V : build A-frag via cross-quad shfl ----
        #pragma unroll
        for (int ks = 0; ks < 4; ++ks) {
            if (ks < ks_lim) {
                const int kA = 2 * ks, kB = 2 * ks + 1;
                unsigned int a0 = (unsigned)__shfl((int)e0[kA], sLo);
                unsigned int a1 = (unsigned)__shfl((int)e1[kA], sLo);
                unsigned int a2 = (unsigned)__shfl((int)e0[kA], sHi);
                unsigned int a3 = (unsigned)__shfl((int)e1[kA], sHi);
                unsigned int b0 = (unsigned)__shfl((int)e0[kB], sLo);
                unsigned int b1 = (unsigned)__shfl((int)e1[kB], sLo);
                unsigned int b2 = (unsigned)__shfl((int)e0[kB], sHi);
                unsigned int b3 = (unsigned)__shfl((int)e1[kB], sHi);
                uint4 pu;
                pu.x = hiSel ? b0 : a0;
                pu.y = hiSel ? b1 : a1;
                pu.z = hiSel ? b2 : a2;
                pu.w = hiSel ? b3 : a3;
                bf16x8 pf = __builtin_bit_cast(bf16x8, pu);
                #pragma unroll
                for (int dt = 0; dt < 4; ++dt) {
                    const int row = dt * 16 + n16;
                    bf16x8 vf = *(const bf16x8*)&Vts[row * BKEY +
                                    (((ks * 4 + quad) ^ n16) * 8)];
                    o[dt] = __builtin_amdgcn_mfma_f32_16x16x32_bf16(pf, vf, o[dt], 0, 0, 0);
                }
            }
        }
    };

    // prologue: K[0] landed + barrier
    stageK(0);
    asm volatile("s_waitcnt vmcnt(0)" ::: "memory");
    __builtin_amdgcn_s_barrier();

    for (int it = 0; it < nIterB; ++it) {
        const int k0 = it * BKEY;
        const bool notLast = (it + 1 < nIterB);

        stageV(it);                         // V[t] -> Vts (write-safe: post-barrier)
        if (notLast) stageK(it + 1);        // K[t+1] -> other buffer, full-iter lead
        const unsigned short* Kb = Ks[it & 1];

        phase(qfB0, qfB1, oB, lsB, wqB, k0, Kb, true,  notLast);
        if (it < nIterA)
            phase(qfA0, qfA1, oA, lsA, wqA, k0, Kb, false, notLast);

        // own K[t+1] landed (hidden under this iter's compute); converge
        asm volatile("s_waitcnt vmcnt(0)" ::: "memory");
        __builtin_amdgcn_s_barrier();
    }

    // ---- final l reduction ----
    lsA += __shfl_xor(lsA, 16); lsA += __shfl_xor(lsA, 32);
    lsB += __shfl_xor(lsB, 16); lsB += __shfl_xor(lsB, 32);

    #pragma unroll
    for (int r = 0; r < 4; ++r) {
        const float invA = 1.f / __shfl(lsA, quad * 4 + r);
        unsigned short* orowA = out + ((size_t)b * T_ + wqA + quad * 4 + r) * E_ + h * D_;
        #pragma unroll
        for (int dt = 0; dt < 4; ++dt)
            orowA[dt * 16 + n16] = f2bf(oA[dt][r] * invA);
        const float invB = 1.f / __shfl(lsB, quad * 4 + r);
        unsigned short* orowB = out + ((size_t)b * T_ + wqB + quad * 4 + r) * E_ + h * D_;
        #pragma unroll
        for (int dt = 0; dt < 4; ++dt)
            orowB[dt * 16 + n16] = f2bf(oB[dt][r] * invB);
    }
}

extern "C" void kernel_launch(void* const* d_in, const int* in_sizes, int n_in,
                              void* d_out, int out_size, void* d_ws, size_t ws_size,
                              hipStream_t stream)
{
    const float* x      = (const float*)d_in[0];
    const float* w_attn = (const float*)d_in[1];
    const float* b_attn = (const float*)d_in[2];
    const float* w_proj = (const float*)d_in[3];
    const float* b_proj = (const float*)d_in[4];
    float* out = (float*)d_out;

    const int M = B_ * T_;  // 8192

    unsigned short* x_bf   = (unsigned short*)d_ws;           // [M,E]
    unsigned short* wat    = x_bf + (size_t)M * E_;           // [3E,E]
    unsigned short* wpt    = wat + (size_t)E3 * E_;           // [E,E]
    unsigned short* qkv_bf = wpt + (size_t)E_ * E_;           // [M,3E] (V region unused)
    unsigned short* att_bf = qkv_bf + (size_t)M * E3;         // [M,E]
    unsigned short* vt_bf  = att_bf + (size_t)M * E_;         // [B*H*64,1024]

    static bool qkv_attr_set = false;
    if (!qkv_attr_set) {
        hipFuncSetAttribute((const void*)gemm_qkv_256,
                            hipFuncAttributeMaxDynamicSharedMemorySize, 131072);
        qkv_attr_set = true;
    }

    prep_kernel<<<NCVT + NTA + NTP, 256, 0, stream>>>(x, x_bf, w_attn, wat, w_proj, wpt);

    gemm_qkv_256<<<dim3(288), dim3(512), 131072, stream>>>(
        x_bf, wat, b_attn, qkv_bf, vt_bf);

    flash_attn_kernel<<<B_ * H_ * 8, 256, 0, stream>>>(qkv_bf, vt_bf, att_bf);

    gemm_mfma_kernel<float, 0, 64, 128, 2, 2>
        <<<dim3(E_ / 128, M / 64), 256, 0, stream>>>(
        att_bf, wpt, b_proj, out, nullptr, M, E_, E_);
}

// Round 5
// 167.239 us; speedup vs baseline: 1.2867x; 1.1149x over previous
//
#include <hip/hip_runtime.h>
#include <math.h>

// GPT attention block: B=8, T=1024, E=768, H=12, D=64. fp32 in/out.
// Round 15 (= R14 with compile fix): QKV GEMM 128x192 tile, 768 blocks
// (= 3 exact dispatch rounds on 256 CUs), LDS 80KiB double-buffer ->
// 2 blocks/CU (16 waves). 2-phase counted-vmcnt loop: per K-tile
// {stage 5 ops of t+1 -> other buf; vmcnt(5); barrier; ds_read; 24 MFMA;
// barrier}. Fix vs R14: no LDS-pointer arrays (addrspacecast static-init
// error) — buffer bases computed by integer offset instead.
// Flash v7 / proj GEMM / prep unchanged.

#define B_ 8
#define T_ 1024
#define E_ 768
#define H_ 12
#define D_ 64
#define E3 (3 * E_)

typedef __attribute__((ext_vector_type(8))) short bf16x8;
typedef __attribute__((ext_vector_type(4))) float f32x4;

#define SCALE 0.18033688f // 0.125 * log2(e)

__device__ __forceinline__ unsigned short f2bf(float f) {
    unsigned int u = __builtin_bit_cast(unsigned int, f);
    u += 0x7fffu + ((u >> 16) & 1u);   // RNE
    return (unsigned short)(u >> 16);
}

__device__ __forceinline__ void async_copy16(void* lds, const void* g) {
    __builtin_amdgcn_global_load_lds(
        (const __attribute__((address_space(1))) void*)g,
        (__attribute__((address_space(3))) void*)lds, 16, 0, 0);
}

// ---------------- fused prep: x->bf16, w_attn^T, w_proj^T ----------------
#define NCVT 6144                 // (8192*768/4)/256
#define NTA  (72 * 24)            // (E3/32) x (E_/32)
#define NTP  (24 * 24)            // (E_/32) x (E_/32)

__device__ __forceinline__ void transpose_tile(
    const float* __restrict__ W, unsigned short* __restrict__ Wt,
    int K, int N, int gx, int gy, unsigned short (*tile)[33])
{
    const int n0 = gx * 32, k0 = gy * 32;
    const int tx = threadIdx.x & 31, ty = threadIdx.x >> 5;
    #pragma unroll
    for (int i = 0; i < 4; ++i)
        tile[ty + i * 8][tx] = f2bf(W[(size_t)(k0 + ty + i * 8) * N + n0 + tx]);
    __syncthreads();
    #pragma unroll
    for (int i = 0; i < 4; ++i)
        Wt[(size_t)(n0 + ty + i * 8) * K + k0 + tx] = tile[tx][ty + i * 8];
}

__global__ __launch_bounds__(256) void prep_kernel(
    const float* __restrict__ x, unsigned short* __restrict__ x_bf,
    const float* __restrict__ w_attn, unsigned short* __restrict__ wat,
    const float* __restrict__ w_proj, unsigned short* __restrict__ wpt)
{
    __shared__ unsigned short tile[32][33];
    const int bid = blockIdx.x;
    if (bid < NCVT) {
        const int i = bid * 256 + threadIdx.x;
        float4 f = ((const float4*)x)[i];
        ushort4 o;
        o.x = f2bf(f.x); o.y = f2bf(f.y); o.z = f2bf(f.z); o.w = f2bf(f.w);
        ((ushort4*)x_bf)[i] = o;
    } else if (bid < NCVT + NTA) {
        const int t = bid - NCVT;
        transpose_tile(w_attn, wat, E_, E3, t % 72, t / 72, tile);
    } else {
        const int t = bid - NCVT - NTA;
        transpose_tile(w_proj, wpt, E_, E_, t % 24, t / 24, tile);
    }
}

// ---------------- QKV GEMM: 128x192 tile, 2-phase counted-vmcnt ----------------
// A = x_bf [8192,768], B = wat [2304,768] (N-major). Grid 768 = 64 x 12 tiles
// = 3 exact rounds of 256 CUs; LDS 80 KiB -> 2 blocks/CU (16 waves).
// 8 waves as 2x4: per-wave rows wm*16 + m*32 (m=0..3), cols wn*16 + n*64
// (n=0..2). acc[4][3] (48 regs). Per K-tile: A 2 + B 3 global_load_lds ops
// per thread; 14 ds_read_b128; 24 MFMA.

__global__ __launch_bounds__(512, 4) void gemm_qkv_128x192(
    const unsigned short* __restrict__ A,   // [8192,768] bf16
    const unsigned short* __restrict__ Wt,  // [2304,768] bf16
    const float* __restrict__ bias,
    unsigned short* __restrict__ C,         // [8192,2304] bf16 (Q,K regions)
    unsigned short* __restrict__ vt)        // [B*H*64,1024] bf16
{
    constexpr int K = 768;
    constexpr int N = E3;
    constexpr int NKT = 12;                 // K / 64

    // layout: [buf0 A 8192][buf1 A 8192][buf0 B 12288][buf1 B 12288] (ushorts)
    extern __shared__ unsigned short lds[];

    const int tid  = threadIdx.x;
    const int lane = tid & 63;
    const int w    = tid >> 6;          // 0..7
    const int wm   = w >> 2;            // 0..1
    const int wn   = w & 3;             // 0..3
    const int n16  = lane & 15;
    const int quad = lane >> 4;
    const int l7   = lane & 7;
    const int lrow = lane >> 3;
    const int lcol = (l7 ^ lrow) * 8;   // pre-swizzled source column group

    // XCD-chunked swizzle: 768 blocks = 8 XCDs x 96; XCD x covers rows of
    // batch x (by = 8x + s/12) -> preserves flash's b-affinity.
    const int lin  = blockIdx.x;
    const int s    = lin >> 3;
    const int by   = (lin & 7) * 8 + s / 12;
    const int bx   = s % 12;
    const int bm = by * 128, bn = bx * 192;

    const unsigned short* Asrc = A  + (size_t)(bm + lrow) * K + lcol;
    const unsigned short* Bsrc = Wt + (size_t)(bn + lrow) * K + lcol;

    auto stage = [&](int bi, int kt) {
        unsigned short* ab = lds + (bi ? 8192 : 0);
        unsigned short* bb = lds + 16384 + (bi ? 12288 : 0);
        #pragma unroll
        for (int i = 0; i < 2; ++i) {
            const int c = w * 2 + i;                  // 0..15 (8 rows each)
            async_copy16(&ab[c * 512], Asrc + (size_t)(c * 8) * K + kt * 64);
        }
        #pragma unroll
        for (int i = 0; i < 3; ++i) {
            const int c = w * 3 + i;                  // 0..23
            async_copy16(&bb[c * 512], Bsrc + (size_t)(c * 8) * K + kt * 64);
        }
    };

    f32x4 acc[4][3] = {};

#define BARR  __builtin_amdgcn_s_barrier()
#define VM5   asm volatile("s_waitcnt vmcnt(5)" ::: "memory")
#define VM0   asm volatile("s_waitcnt vmcnt(0)" ::: "memory")
#define PRI1  __builtin_amdgcn_s_setprio(1)
#define PRI0  __builtin_amdgcn_s_setprio(0)

    stage(0, 0);                        // prologue: tile 0 -> buf0 (5 ops)

    #pragma unroll 1
    for (int u = 0; u < NKT; ++u) {
        const int bi = u & 1;
        const unsigned short* ab = lds + (bi ? 8192 : 0);
        const unsigned short* bb = lds + 16384 + (bi ? 12288 : 0);
        if (u < NKT - 1) {
            stage(bi ^ 1, u + 1);       // 5 ops -> other buffer
            VM5;                        // tile u's 5 ops landed; u+1 in flight
        } else {
            VM0;
        }
        BARR;                           // buf[u] valid for all waves

        #pragma unroll
        for (int kc = 0; kc < 2; ++kc) {
            bf16x8 af[4], bf[3];
            #pragma unroll
            for (int m = 0; m < 4; ++m) {
                const int r = wm * 16 + m * 32 + n16;
                af[m] = *(const bf16x8*)&ab[r * 64 + (((kc * 4 + quad) ^ (r & 7)) * 8)];
            }
            #pragma unroll
            for (int n = 0; n < 3; ++n) {
                const int r = wn * 16 + n * 64 + n16;
                bf[n] = *(const bf16x8*)&bb[r * 64 + (((kc * 4 + quad) ^ (r & 7)) * 8)];
            }
            PRI1;
            #pragma unroll
            for (int m = 0; m < 4; ++m)
                #pragma unroll
                for (int n = 0; n < 3; ++n)
                    acc[m][n] = __builtin_amdgcn_mfma_f32_16x16x32_bf16(
                        af[m], bf[n], acc[m][n], 0, 0, 0);
            PRI0;
        }
        BARR;                           // close reads before next overwrite
    }

#undef VM5
#undef VM0

    // ---- epilogue: col-tiles 0-3 = Q (scaled), 4-7 = K, 8-11 = V -> vt ----
    if (bx >= 8) {
        #pragma unroll
        for (int m = 0; m < 4; ++m) {
            const int tt = bm + wm * 16 + m * 32 + quad * 4;
            const size_t bb2 = (size_t)(tt >> 10) * 768;
            const int tin = tt & 1023;
            #pragma unroll
            for (int n = 0; n < 3; ++n) {
                const int col = bn + wn * 16 + n * 64 + n16;
                const int ch = col - 1536;
                const float bv = bias[col];
                ushort4 o4;
                o4.x = f2bf(acc[m][n][0] + bv);
                o4.y = f2bf(acc[m][n][1] + bv);
                o4.z = f2bf(acc[m][n][2] + bv);
                o4.w = f2bf(acc[m][n][3] + bv);
                *(ushort4*)&vt[(bb2 + ch) * 1024 + tin] = o4;
            }
        }
    } else {
        const bool scale_q = bx < 4;
        #pragma unroll
        for (int m = 0; m < 4; ++m) {
            #pragma unroll
            for (int r = 0; r < 4; ++r) {
                const size_t rowoff = (size_t)(bm + wm * 16 + m * 32 + quad * 4 + r) * N;
                #pragma unroll
                for (int n = 0; n < 3; ++n) {
                    const int col = bn + wn * 16 + n * 64 + n16;
                    float v = acc[m][n][r] + bias[col];
                    if (scale_q) v *= SCALE;
                    C[rowoff + col] = f2bf(v);
                }
            }
        }
    }
}

// ---------------- bf16 MFMA GEMM (proj only, unchanged) ----------------
template <typename OutT, int MODE, int BM, int BN, int WR, int WC>
__global__ __launch_bounds__(256) void gemm_mfma_kernel(
    const unsigned short* __restrict__ A,   // [M,K] bf16
    const unsigned short* __restrict__ Wt,  // [N,K] bf16
    const float* __restrict__ bias,
    OutT* __restrict__ C,
    unsigned short* __restrict__ vt,        // MODE 1 only
    int M, int N, int K)
{
    constexpr int MT = BM / WR / 16;
    constexpr int NT = BN / WC / 16;
    constexpr int CA = BM / 32;
    constexpr int CB = BN / 32;
    constexpr int QBX = 768 / BN;
    constexpr int VBX = 1536 / BN;

    __shared__ unsigned short Abuf[BM * 64];
    __shared__ unsigned short Bbuf[BN * 64];

    const int tid = threadIdx.x;
    const int lane = tid & 63;
    const int w = tid >> 6;
    const int n16 = lane & 15;
    const int quad = lane >> 4;

    const int nbx = gridDim.x;
    const int lin = blockIdx.y * nbx + blockIdx.x;
    const int band_sz = 8 * nbx;
    const int band = lin / band_sz;
    const int rr = lin % band_sz;
    const int bm = (band * 8 + (rr & 7)) * BM;
    const int bx = rr >> 3;
    const int bn = bx * BN;

    const int wmbase = (w / WC) * (BM / WR);
    const int wnbase = (w % WC) * (BN / WC);

    const int lrow = lane >> 3;
    const int lcol = ((lane & 7) ^ lrow) * 8;

    f32x4 acc[MT][NT] = {};

    for (int k0 = 0; k0 < K; k0 += 64) {
        __syncthreads();
        #pragma unroll
        for (int i = 0; i < CA; ++i) {
            const int c = w * CA + i;
            const int row = c * 8 + lrow;
            async_copy16(&Abuf[c * 512], A + (size_t)(bm + row) * K + k0 + lcol);
        }
        #pragma unroll
        for (int i = 0; i < CB; ++i) {
            const int c = w * CB + i;
            const int row = c * 8 + lrow;
            async_copy16(&Bbuf[c * 512], Wt + (size_t)(bn + row) * K + k0 + lcol);
        }
        __syncthreads();

        #pragma unroll
        for (int kc = 0; kc < 2; ++kc) {
            bf16x8 af[MT], bf[NT];
            #pragma unroll
            for (int mt = 0; mt < MT; ++mt) {
                const int r = wmbase + mt * 16 + n16;
                af[mt] = *(const bf16x8*)&Abuf[r * 64 + ((kc * 4 + quad) ^ (r & 7)) * 8];
            }
            #pragma unroll
            for (int nt = 0; nt < NT; ++nt) {
                const int r = wnbase + nt * 16 + n16;
                bf[nt] = *(const bf16x8*)&Bbuf[r * 64 + ((kc * 4 + quad) ^ (r & 7)) * 8];
            }
            #pragma unroll
            for (int mt = 0; mt < MT; ++mt)
                #pragma unroll
                for (int nt = 0; nt < NT; ++nt)
                    acc[mt][nt] = __builtin_amdgcn_mfma_f32_16x16x32_bf16(
                        af[mt], bf[nt], acc[mt][nt], 0, 0, 0);
        }
    }

    if (MODE == 1 && bx >= VBX) {
        #pragma unroll
        for (int mt = 0; mt < MT; ++mt) {
            const int tt = bm + wmbase + mt * 16 + quad * 4;
            const size_t bb = (size_t)(tt >> 10) * 768;
            const int tin = tt & 1023;
            #pragma unroll
            for (int nt = 0; nt < NT; ++nt) {
                const int col = bn + wnbase + nt * 16 + n16;
                const int ch = col - 1536;
                const float bv = bias[col];
                ushort4 o4;
                o4.x = f2bf(acc[mt][nt][0] + bv);
                o4.y = f2bf(acc[mt][nt][1] + bv);
                o4.z = f2bf(acc[mt][nt][2] + bv);
                o4.w = f2bf(acc[mt][nt][3] + bv);
                *(ushort4*)&vt[(bb + ch) * 1024 + tin] = o4;
            }
        }
        return;
    }

    const bool scale_q = (MODE == 1) && (bx < QBX);
    #pragma unroll
    for (int mt = 0; mt < MT; ++mt) {
        #pragma unroll
        for (int r = 0; r < 4; ++r) {
            const size_t rowoff = (size_t)(bm + wmbase + mt * 16 + quad * 4 + r) * N;
            #pragma unroll
            for (int nt = 0; nt < NT; ++nt) {
                const int col = bn + wnbase + nt * 16 + n16;
                float v = acc[mt][nt][r] + bias[col];
                if (scale_q) v *= SCALE;
                if constexpr (sizeof(OutT) == 2) C[rowoff + col] = (OutT)f2bf(v);
                else                             C[rowoff + col] = (OutT)v;
            }
        }
    }
}

// ---------------- Flash attention v7 (unchanged): pipelined LDS staging, no Ps ----------------
#define BKEY 128

__global__ __launch_bounds__(256, 3) void flash_attn_kernel(
    const unsigned short* __restrict__ qkv,
    const unsigned short* __restrict__ vt,   // [(b*H+h)*64+d][1024] bf16
    unsigned short* __restrict__ out)
{
    __shared__ __align__(16) unsigned short Ks[2][BKEY * 64];   // double-buffered K
    __shared__ __align__(16) unsigned short Vts[64 * BKEY];     // single-buffered V^T

    const int tid = threadIdx.x;
    const int idx = blockIdx.x;
    const int xcd = idx & 7;
    const int j   = idx >> 3;           // 0..95
    const int head = xcd * 12 + (j % 12);
    const int p    = j / 12;            // 0..7
    const int h = head % H_;
    const int b = head / H_;

    const int lane = tid & 63;
    const int w    = tid >> 6;
    const int n16  = lane & 15;
    const int quad = lane >> 4;

    const size_t base = (size_t)b * T_ * E3;
    const unsigned short* qbase = qkv + base + h * D_;          // pre-scaled q
    const unsigned short* kbase = qkv + base + E_ + h * D_;
    const unsigned short* vtb   = vt + (size_t)(b * H_ + h) * 64 * 1024;

    const int lrow = lane >> 3;
    const int lcol = ((lane & 7) ^ lrow) * 8;
    const int vr4 = lane >> 4;
    const int vc  = lane & 15;

    const int qtA = p, qtB = 15 - p;
    const int nIterA = (qtA + 2) >> 1;
    const int nIterB = (qtB + 2) >> 1;
    const int wqA = qtA * 64 + w * 16;
    const int wqB = qtB * 64 + w * 16;

    const unsigned short* qrpA = qbase + (size_t)(wqA + n16) * E3 + quad * 8;
    bf16x8 qfA0 = *(const bf16x8*)qrpA;
    bf16x8 qfA1 = *(const bf16x8*)(qrpA + 32);
    const unsigned short* qrpB = qbase + (size_t)(wqB + n16) * E3 + quad * 8;
    bf16x8 qfB0 = *(const bf16x8*)qrpB;
    bf16x8 qfB1 = *(const bf16x8*)(qrpB + 32);

    f32x4 oA[4] = {}, oB[4] = {};
    float lsA = 0.f, lsB = 0.f;

    const int sLo = n16 + 32 * (quad & 1);
    const int sHi = sLo + 16;
    const bool hiSel = quad >= 2;

    auto stageK = [&](int t) {                 // K tile t -> Ks[t&1] (4 loads)
        unsigned short* dst = Ks[t & 1];
        const int k0 = t * BKEY;
        #pragma unroll
        for (int i = 0; i < 4; ++i) {
            const int c = w * 4 + i;
            const int row = c * 8 + lrow;
            async_copy16(&dst[c * 512], kbase + (size_t)(k0 + row) * E3 + lcol);
        }
    };
    auto stageV = [&](int t) {                 // V tile t -> Vts (4 loads)
        const int k0 = t * BKEY;
        #pragma unroll
        for (int i = 0; i < 4; ++i) {
            const int jj = w * 4 + i;
            const int row = 4 * jj + vr4;
            async_copy16(&Vts[4 * jj * BKEY],
                         vtb + (size_t)row * 1024 + k0 + ((vc ^ (row & 15)) * 8));
        }
    };

    auto phase = [&](bf16x8 qf0, bf16x8 qf1, f32x4* o, float& lsum,
                     int wave_q_min, int k0, const unsigned short* Kb,
                     bool doMid, bool notLast) {
        int knt_lim = ((wave_q_min + 15 - k0) >> 4) + 1;
        if (knt_lim > 8) knt_lim = 8;
        const int ks_lim = (knt_lim + 1) >> 1;
        const int nkp = ks_lim * 2;
        int Ab2 = wave_q_min - k0 - 15;
        int kfull = Ab2 < 0 ? 0 : (Ab2 >> 4) + 1;
        if (kfull > 8) kfull = 8;

        const int qcol = wave_q_min + n16;           // this lane's q row

        f32x4 s[8];
        #pragma unroll
        for (int knt = 0; knt < 8; ++knt) {
            if (knt < knt_lim) {
                const int r = knt * 16 + n16;
                bf16x8 kf0 = *(const bf16x8*)&Kb[r * 64 + ((0 + quad) ^ (r & 7)) * 8];
                bf16x8 kf1 = *(const bf16x8*)&Kb[r * 64 + ((4 + quad) ^ (r & 7)) * 8];
                f32x4 acc = {0.f, 0.f, 0.f, 0.f};
                acc = __builtin_amdgcn_mfma_f32_16x16x32_bf16(kf0, qf0, acc, 0, 0, 0);
                acc = __builtin_amdgcn_mfma_f32_16x16x32_bf16(kf1, qf1, acc, 0, 0, 0);
                s[knt] = acc;
            }
        }
        #pragma unroll
        for (int knt = 0; knt < 8; ++knt) {
            if (knt >= kfull && knt < nkp) {
                const int krow = k0 + knt * 16 + quad * 4;
                #pragma unroll
                for (int r = 0; r < 4; ++r) {
                    float v = (knt < knt_lim) ? s[knt][r] : -1e30f;
                    if (krow + r > qcol) v = -1e30f;
                    s[knt][r] = v;
                }
            }
        }

        unsigned int e0[8], e1[8];
        #pragma unroll
        for (int knt = 0; knt < 8; ++knt) {
            if (knt < nkp) {
                float pv0 = __builtin_amdgcn_exp2f(s[knt][0]);
                float pv1 = __builtin_amdgcn_exp2f(s[knt][1]);
                float pv2 = __builtin_amdgcn_exp2f(s[knt][2]);
                float pv3 = __builtin_amdgcn_exp2f(s[knt][3]);
                lsum += (pv0 + pv1) + (pv2 + pv3);
                unsigned int u0 = __builtin_bit_cast(unsigned int, pv0);
                unsigned int u1 = __builtin_bit_cast(unsigned int, pv1);
                unsigned int u2 = __builtin_bit_cast(unsigned int, pv2);
                unsigned int u3 = __builtin_bit_cast(unsigned int, pv3);
                e0[knt] = ((u0 + 0x8000u) >> 16) | ((u1 + 0x8000u) & 0xffff0000u);
                e1[knt] = ((u2 + 0x8000u) >> 16) | ((u3 + 0x8000u) & 0xffff0000u);
            }
        }

        if (doMid) {
            if (notLast) asm volatile("s_waitcnt vmcnt(4)" ::: "memory");
            else         asm volatile("s_waitcnt vmcnt(0)" ::: "memory");
            __builtin_amdgcn_s_barrier();
        }

        #pragma unroll
        for (int ks = 0; ks < 4; ++ks) {
            if (ks < ks_lim) {
                const int kA = 2 * ks, kB = 2 * ks + 1;
                unsigned int a0 = (unsigned)__shfl((int)e0[kA], sLo);
                unsigned int a1 = (unsigned)__shfl((int)e1[kA], sLo);
                unsigned int a2 = (unsigned)__shfl((int)e0[kA], sHi);
                unsigned int a3 = (unsigned)__shfl((int)e1[kA], sHi);
                unsigned int b0 = (unsigned)__shfl((int)e0[kB], sLo);
                unsigned int b1 = (unsigned)__shfl((int)e1[kB], sLo);
                unsigned int b2 = (unsigned)__shfl((int)e0[kB], sHi);
                unsigned int b3 = (unsigned)__shfl((int)e1[kB], sHi);
                uint4 pu;
                pu.x = hiSel ? b0 : a0;
                pu.y = hiSel ? b1 : a1;
                pu.z = hiSel ? b2 : a2;
                pu.w = hiSel ? b3 : a3;
                bf16x8 pf = __builtin_bit_cast(bf16x8, pu);
                #pragma unroll
                for (int dt = 0; dt < 4; ++dt) {
                    const int row = dt * 16 + n16;
                    bf16x8 vf = *(const bf16x8*)&Vts[row * BKEY +
                                    (((ks * 4 + quad) ^ n16) * 8)];
                    o[dt] = __builtin_amdgcn_mfma_f32_16x16x32_bf16(pf, vf, o[dt], 0, 0, 0);
                }
            }
        }
    };

    stageK(0);
    asm volatile("s_waitcnt vmcnt(0)" ::: "memory");
    __builtin_amdgcn_s_barrier();

    for (int it = 0; it < nIterB; ++it) {
        const int k0 = it * BKEY;
        const bool notLast = (it + 1 < nIterB);

        stageV(it);
        if (notLast) stageK(it + 1);
        const unsigned short* Kb = Ks[it & 1];

        phase(qfB0, qfB1, oB, lsB, wqB, k0, Kb, true,  notLast);
        if (it < nIterA)
            phase(qfA0, qfA1, oA, lsA, wqA, k0, Kb, false, notLast);

        asm volatile("s_waitcnt vmcnt(0)" ::: "memory");
        __builtin_amdgcn_s_barrier();
    }

    lsA += __shfl_xor(lsA, 16); lsA += __shfl_xor(lsA, 32);
    lsB += __shfl_xor(lsB, 16); lsB += __shfl_xor(lsB, 32);

    #pragma unroll
    for (int r = 0; r < 4; ++r) {
        const float invA = 1.f / __shfl(lsA, quad * 4 + r);
        unsigned short* orowA = out + ((size_t)b * T_ + wqA + quad * 4 + r) * E_ + h * D_;
        #pragma unroll
        for (int dt = 0; dt < 4; ++dt)
            orowA[dt * 16 + n16] = f2bf(oA[dt][r] * invA);
        const float invB = 1.f / __shfl(lsB, quad * 4 + r);
        unsigned short* orowB = out + ((size_t)b * T_ + wqB + quad * 4 + r) * E_ + h * D_;
        #pragma unroll
        for (int dt = 0; dt < 4; ++dt)
            orowB[dt * 16 + n16] = f2bf(oB[dt][r] * invB);
    }
}

extern "C" void kernel_launch(void* const* d_in, const int* in_sizes, int n_in,
                              void* d_out, int out_size, void* d_ws, size_t ws_size,
                              hipStream_t stream)
{
    const float* x      = (const float*)d_in[0];
    const float* w_attn = (const float*)d_in[1];
    const float* b_attn = (const float*)d_in[2];
    const float* w_proj = (const float*)d_in[3];
    const float* b_proj = (const float*)d_in[4];
    float* out = (float*)d_out;

    const int M = B_ * T_;  // 8192

    unsigned short* x_bf   = (unsigned short*)d_ws;           // [M,E]
    unsigned short* wat    = x_bf + (size_t)M * E_;           // [3E,E]
    unsigned short* wpt    = wat + (size_t)E3 * E_;           // [E,E]
    unsigned short* qkv_bf = wpt + (size_t)E_ * E_;           // [M,3E] (V region unused)
    unsigned short* att_bf = qkv_bf + (size_t)M * E3;         // [M,E]
    unsigned short* vt_bf  = att_bf + (size_t)M * E_;         // [B*H*64,1024]

    static bool qkv_attr_set = false;
    if (!qkv_attr_set) {
        (void)hipFuncSetAttribute((const void*)gemm_qkv_128x192,
                                  hipFuncAttributeMaxDynamicSharedMemorySize, 81920);
        qkv_attr_set = true;
    }

    prep_kernel<<<NCVT + NTA + NTP, 256, 0, stream>>>(x, x_bf, w_attn, wat, w_proj, wpt);

    gemm_qkv_128x192<<<dim3(768), dim3(512), 81920, stream>>>(
        x_bf, wat, b_attn, qkv_bf, vt_bf);

    flash_attn_kernel<<<B_ * H_ * 8, 256, 0, stream>>>(qkv_bf, vt_bf, att_bf);

    gemm_mfma_kernel<float, 0, 64, 128, 2, 2>
        <<<dim3(E_ / 128, M / 64), 256, 0, stream>>>(
        att_bf, wpt, b_proj, out, nullptr, M, E_, E_);
}